// Round 10
// baseline (210.919 us; speedup 1.0000x reference)
//
#include <hip/hip_runtime.h>
#include <stdint.h>

// ---------------- problem constants ----------------
#define B_ROWS 65536
#define D_IN   784
#define H_DIM  256
#define L_LEAF 64
#define C_CLS  10
#define NSTEP2 25            // ceil(784/32) K-steps of 32
#define BTILE2 20480         // 320 n * 32 k * 2B per K-step tile
#define GAP_THRESH 0.03f

using f32x4    = __attribute__((ext_vector_type(4))) float;
using bf16x8   = __attribute__((ext_vector_type(8))) short;
using ushort8v = __attribute__((ext_vector_type(8))) unsigned short;
using ushort4v = __attribute__((ext_vector_type(4))) unsigned short;
using uintx2   = __attribute__((ext_vector_type(2))) unsigned int;

// ---------------- ws layout (bytes) ----------------
#define O_FLAGCNT  0
#define O_CHOICES  4096
#define O_FLAGROWS (O_CHOICES + B_ROWS * 4)
#define O_WT       (O_FLAGROWS + B_ROWS * 4)
#define O_FEAT     (O_WT + NSTEP2 * BTILE2)
#define O_WLB      (O_FEAT + (size_t)B_ROWS * H_DIM * 2)
#define WLB_BYTES  ((size_t)L_LEAF * H_DIM * C_CLS * 2)
#define WS_BASE    O_WLB
#define WS_WLB     (O_WLB + WLB_BYTES)

// K1 LDS geometry: bf16 panel [65 rows alloc][stride 1576B] + B double-buffer
#define PSTRIDE    1576                      // 784*2 + 8 pad (bank-uniform reads)
#define PANEL_PAD  102448                    // 65*1576=102440 -> 16B aligned
#define LDS_TOTAL  (PANEL_PAD + 2 * BTILE2)  // 143,408 <= 160 KiB

__device__ __forceinline__ unsigned short f2bf(float f) {
    union { float f; unsigned int u; } c; c.f = f;
    unsigned int u = c.u;
    return (unsigned short)((u + 0x7fffu + ((u >> 16) & 1u)) >> 16);   // RNE
}
__device__ __forceinline__ float bf2f(unsigned short u) {
    union { unsigned int u; float f; } c; c.u = ((unsigned int)u) << 16;
    return c.f;
}
__device__ __forceinline__ unsigned int cvtpk(float a, float b) {
    unsigned int r;
    asm("v_cvt_pk_bf16_f32 %0, %1, %2" : "=v"(r) : "v"(a), "v"(b));
    return r;
}
__device__ __forceinline__ void gload_lds16(const void* g, void* l) {
    __builtin_amdgcn_global_load_lds(
        (const __attribute__((address_space(1))) unsigned int*)g,
        (__attribute__((address_space(3))) unsigned int*)l, 16, 0, 0);
}

// ---------------- K0: swizzled B image (BK=32), r6-proven ----------------
// chunk (n, c in 0..3) at byte ts*20480 + ((n*64 + c*16) ^ ((n&7)<<4)),
// content k = ts*32 + c*8 (bf16; zero-padded past 784).
__global__ void k0_prep32(const float* __restrict__ Wf, const float* __restrict__ Wr,
                          unsigned short* __restrict__ Wt, unsigned int* __restrict__ flagcnt) {
    if (blockIdx.x == 0 && threadIdx.x == 0) *flagcnt = 0u;
    int id = blockIdx.x * 256 + threadIdx.x;
    int ts = id / 1280;
    int r  = id % 1280;
    int n  = r % 320;
    int c  = r / 320;
    int dst = ts * BTILE2 + ((n * 64 + c * 16) ^ ((n & 7) << 4));
    int ks  = ts * 32 + c * 8;
    unsigned short v[8];
    #pragma unroll
    for (int j = 0; j < 8; ++j) {
        int k = ks + j;
        float f = 0.f;
        if (k < D_IN)
            f = (n < H_DIM) ? Wf[(size_t)k * H_DIM + n]
                            : Wr[(size_t)k * L_LEAF + (n - H_DIM)];
        v[j] = f2bf(f);
    }
    *(ushort8v*)((char*)Wt + dst) = *(ushort8v*)v;
}

// ---------------- K0b: Wl -> bf16 ----------------
__global__ void k0b_wl(const float* __restrict__ Wl, unsigned short* __restrict__ Wlb) {
    int i = (blockIdx.x * 256 + threadIdx.x) * 4;
    f32x4 v = *(const f32x4*)(Wl + i);
    ushort4v h; h.x = f2bf(v.x); h.y = f2bf(v.y); h.z = f2bf(v.z); h.w = f2bf(v.w);
    *(ushort4v*)(Wlb + i) = h;
}

// ---------------- K1: panel-resident dual GEMM ----------------
// grid = 1024 x 512 thr (8 waves = 2M x 4N). Block = 64 rows.
// Phase 1: copy the block's CONTIGUOUS 200KB x-panel -> bf16 LDS panel
//          (one linear stream per block: 256 concurrent streams chip-wide,
//           vs 16K+ strided 128B streams in r1-r9 -> DRAM row locality).
// Phase 2: 25 K-steps entirely from LDS; B staged per-step from L2-hot Wt.
__global__ __launch_bounds__(512, 1) void k1_panel(
    const float* __restrict__ x, const unsigned short* __restrict__ Wt,
    const float* __restrict__ bfv, const float* __restrict__ brv,
    unsigned short* __restrict__ feat, int* __restrict__ choices,
    unsigned int* __restrict__ flagcnt, int* __restrict__ flagrows)
{
    __shared__ __align__(16) char L[LDS_TOTAL];

    const int t = threadIdx.x, w = t >> 6, l = t & 63, q = l >> 4, ic = l & 15;
    const int wm = w >> 2, wn = w & 3;
    const int bm0 = blockIdx.x * 64;
    const int ntb = wn * 5;
    const int e7  = ic & 7;
    const int rbB = (ic * 64 + (q << 4)) ^ (e7 << 4);   // B swizzled offset (r6)

    // ---- stage B(ts=0) into buffer 0
    {
        const char* bs = (const char*)Wt;
        char* bd = L + PANEL_PAD;
        gload_lds16(bs + t * 16,          bd + t * 16);
        gload_lds16(bs + (512 + t) * 16,  bd + (512 + t) * 16);
        if (t < 256)
            gload_lds16(bs + (1024 + t) * 16, bd + (1024 + t) * 16);
    }
    // ---- panel load: 12544 chunks of 16B fp32 (= 64 rows x 3136B, contiguous)
    const float* xp = x + (size_t)bm0 * D_IN;
    #pragma unroll 5
    for (int rd = 0; rd < 25; ++rd) {
        int flat = rd * 512 + t;
        if (flat < 12544) {
            f32x4 v = *(const f32x4*)(xp + (size_t)flat * 4);
            int row  = flat / 196;            // 196 fp32-chunks per row
            int koff = flat - row * 196;      // chunk within row (4 floats)
            uintx2 p;
            p.x = cvtpk(v.x, v.y);
            p.y = cvtpk(v.z, v.w);
            *(uintx2*)(L + row * PSTRIDE + koff * 8) = p;
        }
    }
    __syncthreads();   // panel + B0 visible

    f32x4 acc[2][5];
    #pragma unroll
    for (int a = 0; a < 2; ++a)
        #pragma unroll
        for (int b = 0; b < 5; ++b)
            acc[a][b] = (f32x4){0.f, 0.f, 0.f, 0.f};

    int cur = 0;
    for (int ts = 0; ts < NSTEP2; ++ts) {
        // ---- stage next B tile (overlaps compute; syncthreads drains)
        if (ts + 1 < NSTEP2) {
            const char* bs = (const char*)Wt + (size_t)(ts + 1) * BTILE2;
            char* bd = L + PANEL_PAD + (cur ^ 1) * BTILE2;
            gload_lds16(bs + t * 16,          bd + t * 16);
            gload_lds16(bs + (512 + t) * 16,  bd + (512 + t) * 16);
            if (t < 256)
                gload_lds16(bs + (1024 + t) * 16, bd + (1024 + t) * 16);
        }
        // ---- A fragments from panel (bank-uniform: stride 1576 -> ic*10+4q mod 32)
        const int kg = ts * 32 + q * 8;
        const bool ok = (kg + 8 <= D_IN);     // tail: ts=24, q>=2 -> zero frag
        bf16x8 af[2];
        #pragma unroll
        for (int mt = 0; mt < 2; ++mt) {
            bf16x8 v = *(const bf16x8*)(L + (wm * 32 + mt * 16 + ic) * PSTRIDE
                                          + ts * 64 + q * 16);
            af[mt] = ok ? v : (bf16x8){0,0,0,0,0,0,0,0};
        }
        // ---- MFMA: 5 j x 2 mt
        const char* Bb = L + PANEL_PAD + cur * BTILE2;
        __builtin_amdgcn_s_setprio(1);
        #pragma unroll
        for (int j = 0; j < 5; ++j) {
            bf16x8 b = *(const bf16x8*)(Bb + (ntb + j) * 1024 + rbB);
            acc[0][j] = __builtin_amdgcn_mfma_f32_16x16x32_bf16(af[0], b, acc[0][j], 0, 0, 0);
            acc[1][j] = __builtin_amdgcn_mfma_f32_16x16x32_bf16(af[1], b, acc[1][j], 0, 0, 0);
        }
        __builtin_amdgcn_s_setprio(0);
        __syncthreads();
        cur ^= 1;
    }

    // ---- epilogue: features (cols < 256)
    #pragma unroll
    for (int j = 0; j < 5; ++j) {
        int col = (ntb + j) * 16 + ic;
        if (col < H_DIM) {
            float bias = bfv[col];
            #pragma unroll
            for (int mt = 0; mt < 2; ++mt) {
                #pragma unroll
                for (int i = 0; i < 4; ++i) {
                    int row = bm0 + wm * 32 + mt * 16 + q * 4 + i;
                    float v = acc[mt][j][i] + bias;
                    v = v > 0.f ? v : 0.f;
                    feat[(size_t)row * H_DIM + col] = f2bf(v);
                }
            }
        }
    }
    // ---- router: wn==3 waves hold cols 256..319 in j=1..4
    if (wn == 3) {
        #pragma unroll
        for (int mt = 0; mt < 2; ++mt) {
            #pragma unroll
            for (int i = 0; i < 4; ++i) {
                float m1 = -1e30f, m2 = -1e30f;
                int a1 = 0;
                #pragma unroll
                for (int j = 1; j < 5; ++j) {
                    int leaf = (j - 1) * 16 + ic;
                    float v = acc[mt][j][i] + brv[leaf];
                    if (v > m1) { m2 = m1; m1 = v; a1 = leaf; }
                    else if (v > m2) { m2 = v; }
                }
                #pragma unroll
                for (int s = 1; s < 16; s <<= 1) {
                    float om1 = __shfl_xor(m1, s, 64);
                    float om2 = __shfl_xor(m2, s, 64);
                    int   oa1 = __shfl_xor(a1, s, 64);
                    bool take = (om1 > m1) || (om1 == m1 && oa1 < a1);
                    float nm2 = take ? fmaxf(om2, m1) : fmaxf(m2, om1);
                    m1 = take ? om1 : m1;
                    a1 = take ? oa1 : a1;
                    m2 = nm2;
                }
                if (ic == 0) {
                    int row = bm0 + wm * 32 + mt * 16 + q * 4 + i;
                    choices[row] = a1;
                    if (m1 - m2 < GAP_THRESH) {
                        unsigned int idx = atomicAdd(flagcnt, 1u);
                        flagrows[idx] = row;
                    }
                }
            }
        }
    }
}

// ---------------- K2: exact fp32 router for flagged rows ----------------
__global__ __launch_bounds__(256) void k2_exact(
    const float* __restrict__ x, const float* __restrict__ Wr,
    const float* __restrict__ brv, const unsigned int* __restrict__ flagcnt,
    const int* __restrict__ flagrows, int* __restrict__ choices)
{
    __shared__ float wl[64 * 64];
    __shared__ float xl[4][64];
    const unsigned int cnt = *flagcnt;
    const int t = threadIdx.x, w = t >> 6, l = t & 63;
    for (unsigned int base = blockIdx.x * 4u; base < cnt; base += gridDim.x * 4u) {
        unsigned int ri = base + w;
        int row = (ri < cnt) ? flagrows[ri] : 0;
        const float* xr = x + (size_t)row * D_IN;
        float s0 = 0.f, s1 = 0.f, s2 = 0.f, s3 = 0.f;
        for (int kt = 0; kt < 13; ++kt) {
            int k0 = kt * 64;
            #pragma unroll
            for (int i = 0; i < 4; ++i) {
                int flat = i * 256 + t;
                int kk = flat >> 4, lq = (flat & 15) * 4;
                int kgk = k0 + kk;
                f32x4 v = (f32x4){0.f, 0.f, 0.f, 0.f};
                if (kgk < D_IN) v = *(const f32x4*)(Wr + (size_t)kgk * L_LEAF + lq);
                *(f32x4*)&wl[kk * 64 + lq] = v;
            }
            xl[w][l] = (k0 + l < D_IN) ? xr[k0 + l] : 0.f;
            __syncthreads();
            #pragma unroll
            for (int kk = 0; kk < 64; kk += 4) {
                s0 = fmaf(xl[w][kk    ], wl[(kk    ) * 64 + l], s0);
                s1 = fmaf(xl[w][kk + 1], wl[(kk + 1) * 64 + l], s1);
                s2 = fmaf(xl[w][kk + 2], wl[(kk + 2) * 64 + l], s2);
                s3 = fmaf(xl[w][kk + 3], wl[(kk + 3) * 64 + l], s3);
            }
            __syncthreads();
        }
        float v = (s0 + s1) + (s2 + s3) + brv[l];
        int a = l;
        #pragma unroll
        for (int st = 1; st < 64; st <<= 1) {
            float ov = __shfl_xor(v, st, 64);
            int   oa = __shfl_xor(a, st, 64);
            if (ov > v || (ov == v && oa < a)) { v = ov; a = oa; }
        }
        if (l == 0 && ri < cnt) choices[row] = a;
    }
}

// ---------------- K3: per-row leaf matvec ----------------
__global__ __launch_bounds__(256) void k3_leaf(
    const unsigned short* __restrict__ feat, const int* __restrict__ choices,
    const float* __restrict__ Wl, const unsigned short* __restrict__ Wlb,
    const float* __restrict__ blv, float* __restrict__ out)
{
    const int t = threadIdx.x, wv = t >> 6, l = t & 63, g = l >> 4, i = l & 15;
    const int row = blockIdx.x * 16 + wv * 4 + g;
    const int leaf = choices[row];

    ushort8v f0 = *(const ushort8v*)(feat + (size_t)row * H_DIM + i * 16);
    ushort8v f1 = *(const ushort8v*)(feat + (size_t)row * H_DIM + i * 16 + 8);
    float fv[16];
    #pragma unroll
    for (int j = 0; j < 8; ++j) { fv[j] = bf2f(f0[j]); fv[8 + j] = bf2f(f1[j]); }

    float acc[C_CLS];
    #pragma unroll
    for (int c = 0; c < C_CLS; ++c) acc[c] = 0.f;

    if (Wlb) {
        const unsigned short* wp = Wlb + ((size_t)leaf * H_DIM + i * 16) * C_CLS;
        ushort8v wreg[20];
        #pragma unroll
        for (int j = 0; j < 20; ++j) wreg[j] = *(const ushort8v*)(wp + j * 8);
        #pragma unroll
        for (int h = 0; h < 16; ++h) {
            #pragma unroll
            for (int c = 0; c < C_CLS; ++c) {
                int e = h * C_CLS + c;
                acc[c] = fmaf(fv[h], bf2f(wreg[e >> 3][e & 7]), acc[c]);
            }
        }
    } else {
        const float* wp = Wl + ((size_t)leaf * H_DIM + i * 16) * C_CLS;
        #pragma unroll
        for (int h = 0; h < 16; ++h) {
            #pragma unroll
            for (int c = 0; c < C_CLS; ++c)
                acc[c] = fmaf(fv[h], wp[h * C_CLS + c], acc[c]);
        }
    }
    #pragma unroll
    for (int st = 1; st < 16; st <<= 1) {
        #pragma unroll
        for (int c = 0; c < C_CLS; ++c) acc[c] += __shfl_xor(acc[c], st, 64);
    }
    if (i == 0) {
        #pragma unroll
        for (int c = 0; c < C_CLS; ++c)
            out[(size_t)row * C_CLS + c] = acc[c] + blv[leaf * C_CLS + c];
    }
}

// ---------------- launcher ----------------
extern "C" void kernel_launch(void* const* d_in, const int* in_sizes, int n_in,
                              void* d_out, int out_size, void* d_ws, size_t ws_size,
                              hipStream_t stream) {
    if (ws_size < WS_BASE) return;   // loud fail
    const bool use_bf = ws_size >= WS_WLB;

    const float* x   = (const float*)d_in[0];
    const float* Wf  = (const float*)d_in[1];
    const float* bfv = (const float*)d_in[2];
    const float* Wr  = (const float*)d_in[3];
    const float* brv = (const float*)d_in[4];
    const float* Wl  = (const float*)d_in[5];
    const float* blv = (const float*)d_in[6];
    float* out = (float*)d_out;

    char* ws = (char*)d_ws;
    unsigned int*   flagcnt  = (unsigned int*)(ws + O_FLAGCNT);
    int*            choices  = (int*)(ws + O_CHOICES);
    int*            flagrows = (int*)(ws + O_FLAGROWS);
    unsigned short* Wt       = (unsigned short*)(ws + O_WT);
    unsigned short* feat     = (unsigned short*)(ws + O_FEAT);
    unsigned short* Wlb      = use_bf ? (unsigned short*)(ws + O_WLB) : (unsigned short*)0;

    hipLaunchKernelGGL(k0_prep32, dim3(125), dim3(256), 0, stream, Wf, Wr, Wt, flagcnt);
    if (use_bf)
        hipLaunchKernelGGL(k0b_wl, dim3(160), dim3(256), 0, stream, Wl, Wlb);
    hipLaunchKernelGGL(k1_panel, dim3(B_ROWS / 64), dim3(512), 0, stream,
                       x, Wt, bfv, brv, feat, choices, flagcnt, flagrows);
    hipLaunchKernelGGL(k2_exact, dim3(1024), dim3(256), 0, stream,
                       x, Wr, brv, flagcnt, flagrows, choices);
    hipLaunchKernelGGL(k3_leaf, dim3(B_ROWS / 16), dim3(256), 0, stream,
                       feat, choices, Wl, Wlb, blv, out);
}

// Round 11
// 197.311 us; speedup vs baseline: 1.0690x; 1.0690x over previous
//
#include <hip/hip_runtime.h>
#include <stdint.h>

// ---------------- problem constants ----------------
#define B_ROWS 65536
#define D_IN   784
#define H_DIM  256
#define L_LEAF 64
#define C_CLS  10
#define NSTEP2 25            // ceil(784/32) K-steps of 32
#define BTILE2 20480         // 320 n * 32 k * 2B per K-step tile
#define GAP_THRESH 0.03f

using f32x4    = __attribute__((ext_vector_type(4))) float;
using bf16x8   = __attribute__((ext_vector_type(8))) short;
using ushort8v = __attribute__((ext_vector_type(8))) unsigned short;
using ushort4v = __attribute__((ext_vector_type(4))) unsigned short;

// ---------------- ws layout (bytes) ----------------
#define O_FLAGCNT  0
#define O_CHOICES  4096
#define O_FLAGROWS (O_CHOICES + B_ROWS * 4)
#define O_WT       (O_FLAGROWS + B_ROWS * 4)
#define O_FEAT     (O_WT + NSTEP2 * BTILE2)
#define O_WLB      (O_FEAT + (size_t)B_ROWS * H_DIM * 2)
#define WLB_BYTES  ((size_t)L_LEAF * H_DIM * C_CLS * 2)
#define WS_BASE    O_WLB
#define WS_WLB     (O_WLB + WLB_BYTES)

__device__ __forceinline__ unsigned short f2bf(float f) {
    union { float f; unsigned int u; } c; c.f = f;
    unsigned int u = c.u;
    return (unsigned short)((u + 0x7fffu + ((u >> 16) & 1u)) >> 16);   // RNE
}
__device__ __forceinline__ float bf2f(unsigned short u) {
    union { unsigned int u; float f; } c; c.u = ((unsigned int)u) << 16;
    return c.f;
}
__device__ __forceinline__ unsigned int cvtpk(float a, float b) {
    unsigned int r;
    asm("v_cvt_pk_bf16_f32 %0, %1, %2" : "=v"(r) : "v"(a), "v"(b));
    return r;
}
__device__ __forceinline__ void gload_lds16(const void* g, void* l) {
    __builtin_amdgcn_global_load_lds(
        (const __attribute__((address_space(1))) unsigned int*)g,
        (__attribute__((address_space(3))) unsigned int*)l, 16, 0, 0);
}

// ---------------- K0: swizzled B image (BK=32), r6-proven ----------------
__global__ void k0_prep32(const float* __restrict__ Wf, const float* __restrict__ Wr,
                          unsigned short* __restrict__ Wt, unsigned int* __restrict__ flagcnt) {
    if (blockIdx.x == 0 && threadIdx.x == 0) *flagcnt = 0u;
    int id = blockIdx.x * 256 + threadIdx.x;
    int ts = id / 1280;
    int r  = id % 1280;
    int n  = r % 320;
    int c  = r / 320;
    int dst = ts * BTILE2 + ((n * 64 + c * 16) ^ ((n & 7) << 4));
    int ks  = ts * 32 + c * 8;
    unsigned short v[8];
    #pragma unroll
    for (int j = 0; j < 8; ++j) {
        int k = ks + j;
        float f = 0.f;
        if (k < D_IN)
            f = (n < H_DIM) ? Wf[(size_t)k * H_DIM + n]
                            : Wr[(size_t)k * L_LEAF + (n - H_DIM)];
        v[j] = f2bf(f);
    }
    *(ushort8v*)((char*)Wt + dst) = *(ushort8v*)v;
}

// ---------------- K0b: Wl -> bf16 ----------------
__global__ void k0b_wl(const float* __restrict__ Wl, unsigned short* __restrict__ Wlb) {
    int i = (blockIdx.x * 256 + threadIdx.x) * 4;
    f32x4 v = *(const f32x4*)(Wl + i);
    ushort4v h; h.x = f2bf(v.x); h.y = f2bf(v.y); h.z = f2bf(v.z); h.w = f2bf(v.w);
    *(ushort4v*)(Wlb + i) = h;
}

// ---------------- K1: BM=256, ONE block per CU, ONE round ----------------
// grid = 256 x 512 thr (8 waves = 4M x 2N; wave = 64 rows x 160 cols).
// r9's verified counted-vmcnt 3-deep pipeline, resized:
// BUFB = A(256x32 fp32 = 32KB) + B(20KB) = 52KB; 3-deep = 156KB LDS (1 block/CU).
// Rationale: per-block-step overhead (~1400cy, m103-derived) was the invariant
// wall across r1-r10 (1024 blocks x 25 steps x 4 CU-rounds). This cuts
// scheduled step-slots per CU 100 -> 25.
#define BUFB 53248
__global__ __launch_bounds__(512, 1) void k1_big(
    const float* __restrict__ x, const unsigned short* __restrict__ Wt,
    const float* __restrict__ bfv, const float* __restrict__ brv,
    unsigned short* __restrict__ feat, int* __restrict__ choices,
    unsigned int* __restrict__ flagcnt, int* __restrict__ flagrows)
{
    __shared__ __align__(16) char L[3 * BUFB];   // 159744 B

    const int t  = threadIdx.x;
    const int w  = t >> 6, l = t & 63, q = l >> 4, ic = l & 15;
    const int wm = w >> 1, wn = w & 1;          // 4 M-groups x 2 N-groups
    const int bm0 = blockIdx.x * 256;
    const int ntb = wn * 10;                    // wave's first N-tile (10 tiles)

    f32x4 acc[4][10];
    #pragma unroll
    for (int a = 0; a < 4; ++a)
        #pragma unroll
        for (int b = 0; b < 10; ++b)
            acc[a][b] = (f32x4){0.f, 0.f, 0.f, 0.f};

    const int e7  = ic & 7;
    const int pA0 = ((2 * q)     ^ e7) << 4;    // content fp32-chunk 2q   (k=8q..8q+3)
    const int pA1 = ((2 * q + 1) ^ e7) << 4;    // content fp32-chunk 2q+1 (k=8q+4..8q+7)
    const int rbB = (ic * 64 + (q << 4)) ^ (e7 << 4);   // B swizzled offset (r6)

    // A: 2048 chunks/step (4/thread): chunk i=(r,p): r=i>>3, p=i&7,
    //    content c8 = p ^ (r&7), k = ts*32 + c8*4 fp32 (addr-clamped; B zero-pads).
    // B: 1280 chunks (t, t+512, + t+1024 for t<256), linear from Wt image.
    // Issues/stage: waves 0-3: 4A+3B=7; waves 4-7: 4A+2B=6. vmcnt(6) safe for both.
#define STAGE(TS, LB)                                                          \
    {                                                                          \
        const int ts_ = (TS);                                                  \
        char* Lb_ = (LB);                                                      \
        _Pragma("unroll")                                                      \
        for (int h = 0; h < 4; ++h) {                                          \
            int i_ = h * 512 + t;                                              \
            int r_ = i_ >> 3, p_ = i_ & 7;                                     \
            int c8_ = p_ ^ (r_ & 7);                                           \
            int k_ = ts_ * 32 + c8_ * 4;                                       \
            int ko_ = (k_ + 4 <= D_IN) ? k_ : 0;                               \
            gload_lds16(x + (size_t)(bm0 + r_) * D_IN + ko_, Lb_ + i_ * 16);   \
        }                                                                      \
        const char* bs_ = (const char*)Wt + (size_t)ts_ * BTILE2;              \
        char* bd_ = Lb_ + 32768;                                               \
        gload_lds16(bs_ + t * 16,          bd_ + t * 16);                      \
        gload_lds16(bs_ + (512 + t) * 16,  bd_ + (512 + t) * 16);              \
        if (t < 256)                                                           \
            gload_lds16(bs_ + (1024 + t) * 16, bd_ + (1024 + t) * 16);         \
    }

    // ---- prologue: two tiles in flight
    STAGE(0, L);
    STAGE(1, L + BUFB);

    for (int ts = 0; ts < NSTEP2; ++ts) {
        // own stage(ts) complete; stage(ts+1) may remain in flight (counted)
        if (ts < NSTEP2 - 1)
            asm volatile("s_waitcnt vmcnt(6)\ns_barrier" ::: "memory");
        else
            asm volatile("s_waitcnt vmcnt(0)\ns_barrier" ::: "memory");

        if (ts + 2 < NSTEP2) {
            char* nb = L + ((ts + 2) % 3) * BUFB;
            STAGE(ts + 2, nb);
        }

        const char* Lc = L + (ts % 3) * BUFB;
        // ---- A fragments: fp32 from LDS, cvt_pk to bf16
        const int kg = ts * 32 + q * 8;
        const bool ok = (kg + 8 <= D_IN);       // tail: ts=24, q>=2 -> zero frag
        bf16x8 af[4];
        #pragma unroll
        for (int mt = 0; mt < 4; ++mt) {
            const char* rowp = Lc + (wm * 64 + mt * 16 + ic) * 128;
            f32x4 lo = *(const f32x4*)(rowp + pA0);
            f32x4 hi = *(const f32x4*)(rowp + pA1);
            union { unsigned int u[4]; bf16x8 v; } pk;
            pk.u[0] = ok ? cvtpk(lo.x, lo.y) : 0u;
            pk.u[1] = ok ? cvtpk(lo.z, lo.w) : 0u;
            pk.u[2] = ok ? cvtpk(hi.x, hi.y) : 0u;
            pk.u[3] = ok ? cvtpk(hi.z, hi.w) : 0u;
            af[mt] = pk.v;
        }
        // ---- MFMA cluster: 10 nt x 4 mt (each B frag reused 4x)
        const char* Bb = Lc + 32768;
        __builtin_amdgcn_s_setprio(1);
        #pragma unroll
        for (int nt = 0; nt < 10; ++nt) {
            bf16x8 b = *(const bf16x8*)(Bb + (ntb + nt) * 1024 + rbB);
            #pragma unroll
            for (int mt = 0; mt < 4; ++mt)
                acc[mt][nt] = __builtin_amdgcn_mfma_f32_16x16x32_bf16(af[mt], b, acc[mt][nt], 0, 0, 0);
        }
        __builtin_amdgcn_s_setprio(0);
    }
#undef STAGE

    // ---- epilogue: features (global tiles 0..15)
    #pragma unroll
    for (int nt = 0; nt < 10; ++nt) {
        int col = (ntb + nt) * 16 + ic;
        if (col < H_DIM) {
            float bias = bfv[col];
            #pragma unroll
            for (int mt = 0; mt < 4; ++mt) {
                #pragma unroll
                for (int i = 0; i < 4; ++i) {
                    int row = bm0 + wm * 64 + mt * 16 + q * 4 + i;
                    float v = acc[mt][nt][i] + bias;
                    v = v > 0.f ? v : 0.f;
                    feat[(size_t)row * H_DIM + col] = f2bf(v);
                }
            }
        }
    }
    // ---- router: wn==1 waves hold cols 256..319 in nt=6..9
    if (wn == 1) {
        #pragma unroll
        for (int mt = 0; mt < 4; ++mt) {
            #pragma unroll
            for (int i = 0; i < 4; ++i) {
                float m1 = -1e30f, m2 = -1e30f;
                int a1 = 0;
                #pragma unroll
                for (int nt = 6; nt < 10; ++nt) {
                    int leaf = (nt - 6) * 16 + ic;
                    float v = acc[mt][nt][i] + brv[leaf];
                    if (v > m1) { m2 = m1; m1 = v; a1 = leaf; }
                    else if (v > m2) { m2 = v; }
                }
                #pragma unroll
                for (int s = 1; s < 16; s <<= 1) {
                    float om1 = __shfl_xor(m1, s, 64);
                    float om2 = __shfl_xor(m2, s, 64);
                    int   oa1 = __shfl_xor(a1, s, 64);
                    bool take = (om1 > m1) || (om1 == m1 && oa1 < a1);
                    float nm2 = take ? fmaxf(om2, m1) : fmaxf(m2, om1);
                    m1 = take ? om1 : m1;
                    a1 = take ? oa1 : a1;
                    m2 = nm2;
                }
                if (ic == 0) {
                    int row = bm0 + wm * 64 + mt * 16 + q * 4 + i;
                    choices[row] = a1;
                    if (m1 - m2 < GAP_THRESH) {
                        unsigned int idx = atomicAdd(flagcnt, 1u);
                        flagrows[idx] = row;
                    }
                }
            }
        }
    }
}

// ---------------- K2: exact fp32 router for flagged rows ----------------
__global__ __launch_bounds__(256) void k2_exact(
    const float* __restrict__ x, const float* __restrict__ Wr,
    const float* __restrict__ brv, const unsigned int* __restrict__ flagcnt,
    const int* __restrict__ flagrows, int* __restrict__ choices)
{
    __shared__ float wl[64 * 64];
    __shared__ float xl[4][64];
    const unsigned int cnt = *flagcnt;
    const int t = threadIdx.x, w = t >> 6, l = t & 63;
    for (unsigned int base = blockIdx.x * 4u; base < cnt; base += gridDim.x * 4u) {
        unsigned int ri = base + w;
        int row = (ri < cnt) ? flagrows[ri] : 0;
        const float* xr = x + (size_t)row * D_IN;
        float s0 = 0.f, s1 = 0.f, s2 = 0.f, s3 = 0.f;
        for (int kt = 0; kt < 13; ++kt) {
            int k0 = kt * 64;
            #pragma unroll
            for (int i = 0; i < 4; ++i) {
                int flat = i * 256 + t;
                int kk = flat >> 4, lq = (flat & 15) * 4;
                int kgk = k0 + kk;
                f32x4 v = (f32x4){0.f, 0.f, 0.f, 0.f};
                if (kgk < D_IN) v = *(const f32x4*)(Wr + (size_t)kgk * L_LEAF + lq);
                *(f32x4*)&wl[kk * 64 + lq] = v;
            }
            xl[w][l] = (k0 + l < D_IN) ? xr[k0 + l] : 0.f;
            __syncthreads();
            #pragma unroll
            for (int kk = 0; kk < 64; kk += 4) {
                s0 = fmaf(xl[w][kk    ], wl[(kk    ) * 64 + l], s0);
                s1 = fmaf(xl[w][kk + 1], wl[(kk + 1) * 64 + l], s1);
                s2 = fmaf(xl[w][kk + 2], wl[(kk + 2) * 64 + l], s2);
                s3 = fmaf(xl[w][kk + 3], wl[(kk + 3) * 64 + l], s3);
            }
            __syncthreads();
        }
        float v = (s0 + s1) + (s2 + s3) + brv[l];
        int a = l;
        #pragma unroll
        for (int st = 1; st < 64; st <<= 1) {
            float ov = __shfl_xor(v, st, 64);
            int   oa = __shfl_xor(a, st, 64);
            if (ov > v || (ov == v && oa < a)) { v = ov; a = oa; }
        }
        if (l == 0 && ri < cnt) choices[row] = a;
    }
}

// ---------------- K3: per-row leaf matvec ----------------
__global__ __launch_bounds__(256) void k3_leaf(
    const unsigned short* __restrict__ feat, const int* __restrict__ choices,
    const float* __restrict__ Wl, const unsigned short* __restrict__ Wlb,
    const float* __restrict__ blv, float* __restrict__ out)
{
    const int t = threadIdx.x, wv = t >> 6, l = t & 63, g = l >> 4, i = l & 15;
    const int row = blockIdx.x * 16 + wv * 4 + g;
    const int leaf = choices[row];

    ushort8v f0 = *(const ushort8v*)(feat + (size_t)row * H_DIM + i * 16);
    ushort8v f1 = *(const ushort8v*)(feat + (size_t)row * H_DIM + i * 16 + 8);
    float fv[16];
    #pragma unroll
    for (int j = 0; j < 8; ++j) { fv[j] = bf2f(f0[j]); fv[8 + j] = bf2f(f1[j]); }

    float acc[C_CLS];
    #pragma unroll
    for (int c = 0; c < C_CLS; ++c) acc[c] = 0.f;

    if (Wlb) {
        const unsigned short* wp = Wlb + ((size_t)leaf * H_DIM + i * 16) * C_CLS;
        ushort8v wreg[20];
        #pragma unroll
        for (int j = 0; j < 20; ++j) wreg[j] = *(const ushort8v*)(wp + j * 8);
        #pragma unroll
        for (int h = 0; h < 16; ++h) {
            #pragma unroll
            for (int c = 0; c < C_CLS; ++c) {
                int e = h * C_CLS + c;
                acc[c] = fmaf(fv[h], bf2f(wreg[e >> 3][e & 7]), acc[c]);
            }
        }
    } else {
        const float* wp = Wl + ((size_t)leaf * H_DIM + i * 16) * C_CLS;
        #pragma unroll
        for (int h = 0; h < 16; ++h) {
            #pragma unroll
            for (int c = 0; c < C_CLS; ++c)
                acc[c] = fmaf(fv[h], wp[h * C_CLS + c], acc[c]);
        }
    }
    #pragma unroll
    for (int st = 1; st < 16; st <<= 1) {
        #pragma unroll
        for (int c = 0; c < C_CLS; ++c) acc[c] += __shfl_xor(acc[c], st, 64);
    }
    if (i == 0) {
        #pragma unroll
        for (int c = 0; c < C_CLS; ++c)
            out[(size_t)row * C_CLS + c] = acc[c] + blv[leaf * C_CLS + c];
    }
}

// ---------------- launcher ----------------
extern "C" void kernel_launch(void* const* d_in, const int* in_sizes, int n_in,
                              void* d_out, int out_size, void* d_ws, size_t ws_size,
                              hipStream_t stream) {
    if (ws_size < WS_BASE) return;   // loud fail
    const bool use_bf = ws_size >= WS_WLB;

    const float* x   = (const float*)d_in[0];
    const float* Wf  = (const float*)d_in[1];
    const float* bfv = (const float*)d_in[2];
    const float* Wr  = (const float*)d_in[3];
    const float* brv = (const float*)d_in[4];
    const float* Wl  = (const float*)d_in[5];
    const float* blv = (const float*)d_in[6];
    float* out = (float*)d_out;

    char* ws = (char*)d_ws;
    unsigned int*   flagcnt  = (unsigned int*)(ws + O_FLAGCNT);
    int*            choices  = (int*)(ws + O_CHOICES);
    int*            flagrows = (int*)(ws + O_FLAGROWS);
    unsigned short* Wt       = (unsigned short*)(ws + O_WT);
    unsigned short* feat     = (unsigned short*)(ws + O_FEAT);
    unsigned short* Wlb      = use_bf ? (unsigned short*)(ws + O_WLB) : (unsigned short*)0;

    hipLaunchKernelGGL(k0_prep32, dim3(125), dim3(256), 0, stream, Wf, Wr, Wt, flagcnt);
    if (use_bf)
        hipLaunchKernelGGL(k0b_wl, dim3(160), dim3(256), 0, stream, Wl, Wlb);
    hipLaunchKernelGGL(k1_big, dim3(B_ROWS / 256), dim3(512), 0, stream,
                       x, Wt, bfv, brv, feat, choices, flagcnt, flagrows);
    hipLaunchKernelGGL(k2_exact, dim3(1024), dim3(256), 0, stream,
                       x, Wr, brv, flagcnt, flagrows, choices);
    hipLaunchKernelGGL(k3_leaf, dim3(B_ROWS / 16), dim3(256), 0, stream,
                       feat, choices, Wl, Wlb, blv, out);
}